// Round 4
// baseline (664.501 us; speedup 1.0000x reference)
//
#include <hip/hip_runtime.h>
#include <hip/hip_bf16.h>

#define DIM 128
#define NLAYER 4
#define NPB 32            // nodes per block (fused kernel)
#define THREADS 512

typedef _Float16 f16x8 __attribute__((ext_vector_type(8)));
typedef _Float16 f16x2 __attribute__((ext_vector_type(2)));
typedef float f32x4 __attribute__((ext_vector_type(4)));

// ---------------- CSR build ----------------

__global__ void k_count(const int* __restrict__ dst, int E, int* __restrict__ counts) {
    int e = blockIdx.x * blockDim.x + threadIdx.x;
    if (e < E) atomicAdd(&counts[dst[e]], 1);
}

__global__ __launch_bounds__(1024) void k_scan1(const int* __restrict__ in, int n,
                                                int* __restrict__ partial,
                                                int* __restrict__ blockSums) {
    __shared__ int sd[1024];
    int tid = threadIdx.x;
    int i = blockIdx.x * 1024 + tid;
    int v = (i < n) ? in[i] : 0;
    sd[tid] = v;
    __syncthreads();
    for (int off = 1; off < 1024; off <<= 1) {
        int t = (tid >= off) ? sd[tid - off] : 0;
        __syncthreads();
        sd[tid] += t;
        __syncthreads();
    }
    if (i < n) partial[i] = sd[tid];
    if (tid == 1023) blockSums[blockIdx.x] = sd[1023];
}

__global__ void k_scan2(int* __restrict__ bs, int nb) {
    int lane = threadIdx.x;
    int v = (lane < nb) ? bs[lane] : 0;
    for (int off = 1; off < 64; off <<= 1) {
        int t = __shfl_up(v, off, 64);
        if (lane >= off) v += t;
    }
    int ex = __shfl_up(v, 1, 64);
    if (lane == 0) ex = 0;
    if (lane < nb) bs[lane] = ex;
}

__global__ __launch_bounds__(1024) void k_scan3(const int* __restrict__ partial,
                                                const int* __restrict__ bs, int n,
                                                int* __restrict__ row_ptr,
                                                int* __restrict__ cursor) {
    int i = blockIdx.x * blockDim.x + threadIdx.x;
    if (i < n) {
        int v = partial[i] + bs[i >> 10];
        row_ptr[i + 1] = v;
        cursor[i + 1] = v;
    }
    if (i == 0) { row_ptr[0] = 0; cursor[0] = 0; }
}

__global__ void k_scatter(const int* __restrict__ srcA, const int* __restrict__ dstA,
                          const int* __restrict__ typA, const int* __restrict__ hopA,
                          int E, int* __restrict__ cursor, unsigned* __restrict__ csr) {
    int e = blockIdx.x * blockDim.x + threadIdx.x;
    if (e < E) {
        int d = dstA[e];
        int p = atomicAdd(&cursor[d], 1);
        csr[p] = (unsigned)srcA[e] | ((unsigned)typA[e] << 16) | ((unsigned)hopA[e] << 18);
    }
}

__global__ void k_bias(const float* __restrict__ b_edge, const float* __restrict__ b_hop,
                       float* __restrict__ bias_sums) {
    int t = blockIdx.x, d = threadIdx.x;
    float s = b_edge[d] + b_edge[DIM + d] + b_edge[2 * DIM + d];
    int base = t * (t + 1) / 2;
    for (int k = 1; k <= t + 1; ++k) s += b_hop[(base + k - 1) * DIM + d];
    bias_sums[t * DIM + d] = s;
}

// ---------------- f16 conversions ----------------

__global__ void k_convX(const float* __restrict__ in, _Float16* __restrict__ out, int n) {
    int i = (blockIdx.x * blockDim.x + threadIdx.x) * 8;
    if (i >= n) return;
    float4 a = ((const float4*)(in + i))[0];
    float4 b = ((const float4*)(in + i))[1];
    f16x8 o;
    o[0] = (_Float16)a.x; o[1] = (_Float16)a.y; o[2] = (_Float16)a.z; o[3] = (_Float16)a.w;
    o[4] = (_Float16)b.x; o[5] = (_Float16)b.y; o[6] = (_Float16)b.z; o[7] = (_Float16)b.w;
    *(f16x8*)(out + i) = o;
}

// 13 weight matrices, fp32 row-major [k][n] -> f16 transposed [n][k]
__global__ __launch_bounds__(256) void k_convW(const float* __restrict__ W_edge,
                                               const float* __restrict__ W_hop,
                                               _Float16* __restrict__ Wt) {
    int s = blockIdx.x;
    const float* src = (s < 3) ? (W_edge + (size_t)s * DIM * DIM)
                               : (W_hop + (size_t)(s - 3) * DIM * DIM);
    _Float16* dstp = Wt + (size_t)s * DIM * DIM;
    for (int it = 0; it < 64; ++it) {
        int e = it * 256 + threadIdx.x;
        int n = e >> 7, k = e & 127;
        dstp[e] = (_Float16)src[k * DIM + n];
    }
}

// ======== fused: CSR gather -> LDS A tiles -> MFMA -> epilogue ========
// A slot map: 0..2 = edge types, 3+(k-1) = hop k

struct FusedArgs {
    const _Float16* xt;    // xh[t]   (types + hop1 + residual)
    const _Float16* xm1;   // xh[t-1] (hop2)
    const _Float16* xm2;   // xh[t-2] (hop3)
    const _Float16* xm3;   // xh[t-3] (hop4)
    const _Float16* Wt;    // 13 x [n][k] f16
    const float* bias;     // bias_sums + t*128
    float* outf;           // fp32 out (final layer) or null
    _Float16* outh;        // xh[t+1] or null
    const int* row_ptr;
    const unsigned* csr;
    int t, N;
};

__global__ __launch_bounds__(THREADS, 4) void k_fused(FusedArgs a) {
    __shared__ __align__(16) _Float16 Alds[7][NPB][DIM];   // 57344 B, XOR-swizzled rows
    __shared__ float Clds[NPB][DIM + 4];                   // 16896 B, padded

    const int tid = threadIdx.x, wid = tid >> 6, lane = tid & 63;
    const int nodeBase = blockIdx.x * NPB;
    const int hopMax = a.t + 1;

    // ---------------- gather phase: 4 nodes per wave ----------------
    #pragma unroll
    for (int i = 0; i < 4; ++i) {
        const int lrow = wid * 4 + i;
        const int node = nodeBase + lrow;
        int e0 = 0, e1 = 0;
        if (node < a.N) { e0 = a.row_ptr[node]; e1 = a.row_ptr[node + 1]; }

        float t0x = 0, t0y = 0, t1x = 0, t1y = 0, t2x = 0, t2y = 0;
        float h1x = 0, h1y = 0, h2x = 0, h2y = 0, h3x = 0, h3y = 0, h4x = 0, h4y = 0;

        int e = e0;
        const int e4 = e0 + ((e1 - e0) & ~3);
        for (; e < e4; e += 4) {
            unsigned mm[4];
            #pragma unroll
            for (int j = 0; j < 4; ++j) mm[j] = a.csr[e + j];
            f16x2 vv[4], ww[4];
            #pragma unroll
            for (int j = 0; j < 4; ++j) {
                int src = mm[j] & 0xFFFF;
                int hop = (int)(mm[j] >> 18);
                vv[j] = ((const f16x2*)(a.xt + (size_t)src * DIM))[lane];
                const _Float16* ph = (hop == 2) ? a.xm1 : (hop == 3) ? a.xm2 : a.xt;
                ph = (hop == 4) ? a.xm3 : ph;
                ww[j] = ((const f16x2*)(ph + (size_t)src * DIM))[lane];
            }
            #pragma unroll
            for (int j = 0; j < 4; ++j) {
                int typ = (mm[j] >> 16) & 3;
                int hop = (int)(mm[j] >> 18);
                float vx = (float)vv[j][0], vy = (float)vv[j][1];
                t0x += (typ == 0) ? vx : 0.f; t0y += (typ == 0) ? vy : 0.f;
                t1x += (typ == 1) ? vx : 0.f; t1y += (typ == 1) ? vy : 0.f;
                t2x += (typ == 2) ? vx : 0.f; t2y += (typ == 2) ? vy : 0.f;
                bool hv = (hop >= 1) && (hop <= hopMax);
                float wx = hv ? (float)ww[j][0] : 0.f;
                float wy = hv ? (float)ww[j][1] : 0.f;
                h1x += (hop == 1) ? wx : 0.f; h1y += (hop == 1) ? wy : 0.f;
                h2x += (hop == 2) ? wx : 0.f; h2y += (hop == 2) ? wy : 0.f;
                h3x += (hop == 3) ? wx : 0.f; h3y += (hop == 3) ? wy : 0.f;
                h4x += (hop == 4) ? wx : 0.f; h4y += (hop == 4) ? wy : 0.f;
            }
        }
        for (; e < e1; ++e) {
            unsigned m = a.csr[e];
            int src = m & 0xFFFF;
            int typ = (m >> 16) & 3;
            int hop = (int)(m >> 18);
            f16x2 v = ((const f16x2*)(a.xt + (size_t)src * DIM))[lane];
            const _Float16* ph = (hop == 2) ? a.xm1 : (hop == 3) ? a.xm2 : a.xt;
            ph = (hop == 4) ? a.xm3 : ph;
            f16x2 w = ((const f16x2*)(ph + (size_t)src * DIM))[lane];
            float vx = (float)v[0], vy = (float)v[1];
            t0x += (typ == 0) ? vx : 0.f; t0y += (typ == 0) ? vy : 0.f;
            t1x += (typ == 1) ? vx : 0.f; t1y += (typ == 1) ? vy : 0.f;
            t2x += (typ == 2) ? vx : 0.f; t2y += (typ == 2) ? vy : 0.f;
            bool hv = (hop >= 1) && (hop <= hopMax);
            float wx = hv ? (float)w[0] : 0.f;
            float wy = hv ? (float)w[1] : 0.f;
            h1x += (hop == 1) ? wx : 0.f; h1y += (hop == 1) ? wy : 0.f;
            h2x += (hop == 2) ? wx : 0.f; h2y += (hop == 2) ? wy : 0.f;
            h3x += (hop == 3) ? wx : 0.f; h3y += (hop == 3) ? wy : 0.f;
            h4x += (hop == 4) ? wx : 0.f; h4y += (hop == 4) ? wy : 0.f;
        }

        // write 7 slot rows to LDS, XOR-swizzled within the 256B row
        const int rbyte = lrow * (DIM * 2);
        const int cb = (lane * 4) ^ ((lrow & 7) << 4);
        char* base = (char*)&Alds[0][0][0] + rbyte + cb;
        f16x2 o;
        o[0] = (_Float16)t0x; o[1] = (_Float16)t0y; *(f16x2*)(base + 0 * sizeof(Alds[0])) = o;
        o[0] = (_Float16)t1x; o[1] = (_Float16)t1y; *(f16x2*)(base + 1 * sizeof(Alds[0])) = o;
        o[0] = (_Float16)t2x; o[1] = (_Float16)t2y; *(f16x2*)(base + 2 * sizeof(Alds[0])) = o;
        o[0] = (_Float16)h1x; o[1] = (_Float16)h1y; *(f16x2*)(base + 3 * sizeof(Alds[0])) = o;
        o[0] = (_Float16)h2x; o[1] = (_Float16)h2y; *(f16x2*)(base + 4 * sizeof(Alds[0])) = o;
        o[0] = (_Float16)h3x; o[1] = (_Float16)h3y; *(f16x2*)(base + 5 * sizeof(Alds[0])) = o;
        o[0] = (_Float16)h4x; o[1] = (_Float16)h4y; *(f16x2*)(base + 6 * sizeof(Alds[0])) = o;
    }
    __syncthreads();

    // ---------------- MFMA phase ----------------
    // wave -> (row-tile rt = wid>>2, col-tiles ct0,ct0+1 with ct0=(wid&3)*2)
    {
        const int rt = wid >> 2;
        const int ct0 = (wid & 3) * 2;
        const int lr = lane & 15, lg = lane >> 4;
        const int nsub = a.t + 4;
        const int row = rt * 16 + lr;
        const int rowOff = row * (DIM * 2);
        const int rswz = (row & 7) << 4;

        f32x4 acc0 = {0.f, 0.f, 0.f, 0.f}, acc1 = {0.f, 0.f, 0.f, 0.f};
        for (int s = 0; s < nsub; ++s) {
            const _Float16* Bs = a.Wt +
                (size_t)((s < 3) ? s : (a.t * (a.t + 1) / 2 + s)) * (DIM * DIM);
            const char* As = (const char*)&Alds[s][0][0] + rowOff;
            #pragma unroll
            for (int ks = 0; ks < 4; ++ks) {
                int kb = ks * 32 + lg * 8;                    // in halves
                f16x8 af = *(const f16x8*)(As + ((kb * 2) ^ rswz));
                f16x8 b0 = *(const f16x8*)(Bs + (size_t)((ct0 + 0) * 16 + lr) * DIM + kb);
                f16x8 b1 = *(const f16x8*)(Bs + (size_t)((ct0 + 1) * 16 + lr) * DIM + kb);
                acc0 = __builtin_amdgcn_mfma_f32_16x16x32_f16(af, b0, acc0, 0, 0, 0);
                acc1 = __builtin_amdgcn_mfma_f32_16x16x32_f16(af, b1, acc1, 0, 0, 0);
            }
        }
        // C layout: col = lane&15, row = (lane>>4)*4 + rg
        #pragma unroll
        for (int rg = 0; rg < 4; ++rg) {
            int crow = rt * 16 + lg * 4 + rg;
            Clds[crow][(ct0 + 0) * 16 + lr] = acc0[rg];
            Clds[crow][(ct0 + 1) * 16 + lr] = acc1[rg];
        }
    }
    __syncthreads();

    // ---------------- epilogue: bias+relu+residual+L2 normalize ----------------
    {
        const int c0 = lane * 2;
        float b0 = a.bias[c0], b1 = a.bias[c0 + 1];
        #pragma unroll
        for (int i = 0; i < 4; ++i) {
            int lrow = wid * 4 + i;
            int node = nodeBase + lrow;
            float u0 = Clds[lrow][c0], u1 = Clds[lrow][c0 + 1];
            float x0 = 0.f, x1 = 0.f;
            if (node < a.N) {
                f16x2 xv = ((const f16x2*)(a.xt + (size_t)node * DIM))[lane];
                x0 = (float)xv[0]; x1 = (float)xv[1];
            }
            float v0 = x0 + fmaxf(u0 + b0, 0.f);
            float v1 = x1 + fmaxf(u1 + b1, 0.f);
            float ss = v0 * v0 + v1 * v1;
            ss += __shfl_xor(ss, 1, 64);
            ss += __shfl_xor(ss, 2, 64);
            ss += __shfl_xor(ss, 4, 64);
            ss += __shfl_xor(ss, 8, 64);
            ss += __shfl_xor(ss, 16, 64);
            ss += __shfl_xor(ss, 32, 64);
            float inv = 1.f / fmaxf(sqrtf(ss), 1e-12f);
            v0 *= inv; v1 *= inv;
            if (node < a.N) {
                if (a.outf) ((float2*)(a.outf + (size_t)node * DIM))[lane] = make_float2(v0, v1);
                if (a.outh) {
                    f16x2 o; o[0] = (_Float16)v0; o[1] = (_Float16)v1;
                    ((f16x2*)(a.outh + (size_t)node * DIM))[lane] = o;
                }
            }
        }
    }
}

// ---------------- launch ----------------

static inline size_t align_up(size_t v, size_t a) { return (v + a - 1) & ~(a - 1); }

extern "C" void kernel_launch(void* const* d_in, const int* in_sizes, int n_in,
                              void* d_out, int out_size, void* d_ws, size_t ws_size,
                              hipStream_t stream) {
    const float* x        = (const float*)d_in[0];
    const int* edge_index = (const int*)d_in[1];
    const int* edge_hop   = (const int*)d_in[2];
    const int* edge_type  = (const int*)d_in[3];
    const float* W_edge   = (const float*)d_in[4];
    const float* b_edge   = (const float*)d_in[5];
    const float* W_hop    = (const float*)d_in[6];
    const float* b_hop    = (const float*)d_in[7];
    float* out = (float*)d_out;

    int N = in_sizes[0] / DIM;   // 50000
    int E = in_sizes[2];         // 600000
    const int* srcA = edge_index;
    const int* dstA = edge_index + E;

    size_t NSh = (size_t)N * DIM * sizeof(_Float16);
    size_t off = 0;
    char* wsb = (char*)d_ws;
    _Float16* xh0     = (_Float16*)(wsb + off);  off = align_up(off + NSh, 64);
    _Float16* xh1     = (_Float16*)(wsb + off);  off = align_up(off + NSh, 64);
    _Float16* xh2     = (_Float16*)(wsb + off);  off = align_up(off + NSh, 64);
    _Float16* xh3     = (_Float16*)(wsb + off);  off = align_up(off + NSh, 64);
    _Float16* Wt      = (_Float16*)(wsb + off);  off = align_up(off + 13 * DIM * DIM * sizeof(_Float16), 64);
    int* counts       = (int*)(wsb + off);       off = align_up(off + (size_t)N * 4, 64);
    int* partial      = (int*)(wsb + off);       off = align_up(off + (size_t)N * 4, 64);
    int* blockSums    = (int*)(wsb + off);       off = align_up(off + 64 * 4, 64);
    int* row_ptr      = (int*)(wsb + off);       off = align_up(off + (size_t)(N + 1) * 4, 64);
    int* cursor       = (int*)(wsb + off);       off = align_up(off + (size_t)(N + 1) * 4, 64);
    unsigned* csr     = (unsigned*)(wsb + off);  off = align_up(off + (size_t)E * 4, 64);
    float* bias_sums  = (float*)(wsb + off);     off = align_up(off + 4 * DIM * 4, 64);
    (void)ws_size;  // ~56 MB

    // CSR build
    hipMemsetAsync(counts, 0, (size_t)N * 4, stream);
    k_count<<<(E + 255) / 256, 256, 0, stream>>>(dstA, E, counts);
    int nb = (N + 1023) / 1024;
    k_scan1<<<nb, 1024, 0, stream>>>(counts, N, partial, blockSums);
    k_scan2<<<1, 64, 0, stream>>>(blockSums, nb);
    k_scan3<<<nb, 1024, 0, stream>>>(partial, blockSums, N, row_ptr, cursor);
    k_scatter<<<(E + 255) / 256, 256, 0, stream>>>(srcA, dstA, edge_type, edge_hop, E, cursor, csr);
    k_bias<<<4, DIM, 0, stream>>>(b_edge, b_hop, bias_sums);

    // f16 conversions
    k_convX<<<(N * DIM / 8 + 255) / 256, 256, 0, stream>>>(x, xh0, N * DIM);
    k_convW<<<13, 256, 0, stream>>>(W_edge, W_hop, Wt);

    _Float16* xh_ptr[4] = { xh0, xh1, xh2, xh3 };

    for (int t = 0; t < NLAYER; ++t) {
        FusedArgs f;
        f.xt  = xh_ptr[t];
        f.xm1 = (t >= 1) ? xh_ptr[t - 1] : xh0;
        f.xm2 = (t >= 2) ? xh_ptr[t - 2] : xh0;
        f.xm3 = (t >= 3) ? xh_ptr[t - 3] : xh0;
        f.Wt = Wt;
        f.bias = bias_sums + t * DIM;
        f.outf = (t == 3) ? out : nullptr;
        f.outh = (t < 3) ? xh_ptr[t + 1] : nullptr;
        f.row_ptr = row_ptr; f.csr = csr; f.t = t; f.N = N;
        k_fused<<<(N + NPB - 1) / NPB, THREADS, 0, stream>>>(f);
    }
}